// Round 5
// baseline (253.879 us; speedup 1.0000x reference)
//
#include <hip/hip_runtime.h>

// Problem constants (from reference): A=5, B=2, K=5, C=13, H=W=256
constexpr int A_ = 5, B_ = 2, K_ = 5, C_ = 13, H_ = 256, W_ = 256;
constexpr int HW_ = H_ * W_;
constexpr int TILE = 16;
constexpr int REG = TILE + 1;             // 17 (tile + 1 halo for pass-2 taps)
constexpr int NPOS = REG * REG;           // 289
constexpr int NT = 256;
constexpr int PPT = 2;                    // ceil(289/256)
constexpr int BCAP = 2048;                // bbox LDS capacity in floats (8 KB)

__global__ __launch_bounds__(NT)
void fafmimo_warp_kernel(const float* __restrict__ bevs,
                         const float* __restrict__ tm,
                         const int*   __restrict__ nat,
                         const int*   __restrict__ center_p,
                         float* __restrict__ out)
{
    const int tileIdx = blockIdx.x;       // 0..255 (16x16 tiles of 16x16 px)
    const int abk     = blockIdx.y;       // 0..49 == (a*B+b)*K + k
    const int ch      = blockIdx.z;       // 0..12
    const int a   = abk / (B_ * K_);
    const int rem = abk % (B_ * K_);
    const int b   = rem / K_;
    const int k   = rem % K_;

    const int center  = center_p[0];
    const int n_agent = nat[b * A_ + center];
    const bool masked = (a < n_agent) && ((a != center) || (k == K_ - 1));

    const int th0 = (tileIdx >> 4) * TILE;
    const int tw0 = (tileIdx & 15) * TILE;

    const int tid  = threadIdx.x;
    const int pr_o = tid >> 4;            // output row within tile
    const int pc_o = tid & 15;            // output col within tile
    const int pix  = (th0 + pr_o) * W_ + tw0 + pc_o;

    const float* __restrict__ img = bevs + (size_t)(abk * C_ + ch) * HW_;
    float*       __restrict__ o   = out  + (size_t)(abk * C_ + ch) * HW_;

    if (!masked) {
        o[pix] = img[pix];                // coalesced 1:1 copy
        return;
    }

    // --- per-image transform params (trans_mats shape (A,K,B,4,4)) ---
    const int tb = ((a * K_ + k) * B_ + b) * 16;
    const float t00 = tm[tb + 0], t01 = tm[tb + 1], t03 = tm[tb + 3];
    const float t10 = tm[tb + 4], t11 = tm[tb + 5], t13 = tm[tb + 7];

    // Pass-2 (translation) in pixel units
    const float dx = 4.0f * t03;
    const float dy = -4.0f * t13;
    const float fxf = floorf(dx), fyf = floorf(dy);
    const int   fx = (int)fxf,    fy = (int)fyf;
    const float wx2 = dx - fxf,   wy2 = dy - fyf;
    const float w00 = (1.0f - wx2) * (1.0f - wy2);
    const float w01 = wx2 * (1.0f - wy2);
    const float w10 = (1.0f - wx2) * wy2;
    const float w11 = wx2 * wy2;

    // source coords: ix = t00*gx + t01*gy + cxk  (verified formula, R3/R4)
    const float cxk = 127.5f - 127.5f * (t00 + t01);
    const float cyk = 127.5f - 127.5f * (t10 + t11);

    // --- pass-1 taps for the 17x17 S1 region (channel-independent) ---
    int   cx0a[PPT], cx1a[PPT], cy0a[PPT], cy1a[PPT];
    float q0[PPT], q1[PPT], q2[PPT], q3[PPT];
    int mnx = 0x7fffffff, mxx = -0x7fffffff;
    int mny = 0x7fffffff, mxy = -0x7fffffff;
    #pragma unroll
    for (int it = 0; it < PPT; ++it) {
        const int p = tid + it * NT;
        const int pr = p / REG;
        const int pc = p - pr * REG;
        const int gyp = th0 + fy + pr;
        const int gxp = tw0 + fx + pc;
        const bool inreg = (p < NPOS) &&
                           (gyp >= 0) && (gyp < H_) && (gxp >= 0) && (gxp < W_);
        const float ix = t00 * (float)gxp + t01 * (float)gyp + cxk;
        const float iy = t10 * (float)gxp + t11 * (float)gyp + cyk;
        const float x0f = floorf(ix), y0f = floorf(iy);
        const float wx = ix - x0f,    wy = iy - y0f;
        const int x0 = (int)x0f, y0 = (int)y0f;
        const int x1 = x0 + 1,   y1 = y0 + 1;
        const bool vx0 = (x0 >= 0) && (x0 < W_);
        const bool vx1 = (x1 >= 0) && (x1 < W_);
        const bool vy0 = (y0 >= 0) && (y0 < H_);
        const bool vy1 = (y1 >= 0) && (y1 < H_);
        const int cx0 = min(max(x0, 0), W_ - 1);
        const int cx1 = min(max(x1, 0), W_ - 1);
        const int cy0 = min(max(y0, 0), H_ - 1);
        const int cy1 = min(max(y1, 0), H_ - 1);
        cx0a[it] = cx0; cx1a[it] = cx1; cy0a[it] = cy0; cy1a[it] = cy1;
        const float m = inreg ? 1.0f : 0.0f;
        q0[it] = (1.0f - wx) * (1.0f - wy) * ((vx0 && vy0) ? m : 0.0f);
        q1[it] = wx * (1.0f - wy)          * ((vx1 && vy0) ? m : 0.0f);
        q2[it] = (1.0f - wx) * wy          * ((vx0 && vy1) ? m : 0.0f);
        q3[it] = wx * wy                   * ((vx1 && vy1) ? m : 0.0f);
        // hull over nonzero-weight taps only (exact support bbox)
        if (q0[it] != 0.f) { mnx = min(mnx, cx0); mxx = max(mxx, cx0);
                             mny = min(mny, cy0); mxy = max(mxy, cy0); }
        if (q1[it] != 0.f) { mnx = min(mnx, cx1); mxx = max(mxx, cx1);
                             mny = min(mny, cy0); mxy = max(mxy, cy0); }
        if (q2[it] != 0.f) { mnx = min(mnx, cx0); mxx = max(mxx, cx0);
                             mny = min(mny, cy1); mxy = max(mxy, cy1); }
        if (q3[it] != 0.f) { mnx = min(mnx, cx1); mxx = max(mxx, cx1);
                             mny = min(mny, cy1); mxy = max(mxy, cy1); }
    }

    // --- block reduction of the support hull ---
    #pragma unroll
    for (int d = 32; d > 0; d >>= 1) {
        mnx = min(mnx, __shfl_xor(mnx, d));
        mxx = max(mxx, __shfl_xor(mxx, d));
        mny = min(mny, __shfl_xor(mny, d));
        mxy = max(mxy, __shfl_xor(mxy, d));
    }
    __shared__ int red[4][4];
    __shared__ float sBox[BCAP];
    __shared__ float sS1[NPOS];
    const int wid = tid >> 6;
    if ((tid & 63) == 0) {
        red[wid][0] = mnx; red[wid][1] = mxx;
        red[wid][2] = mny; red[wid][3] = mxy;
    }
    __syncthreads();
    mnx = min(min(red[0][0], red[1][0]), min(red[2][0], red[3][0]));
    mxx = max(max(red[0][1], red[1][1]), max(red[2][1], red[3][1]));
    mny = min(min(red[0][2], red[1][2]), min(red[2][2], red[3][2]));
    mxy = max(max(red[0][3], red[1][3]), max(red[2][3], red[3][3]));

    if (mxx < 0) {                        // no nonzero-weight tap in tile
        o[pix] = 0.0f;
        return;
    }

    const int Lw   = mxx - mnx + 1;
    const int nry  = mxy - mny + 1;
    const bool fit = (Lw * nry <= BCAP);

    if (fit) {
        // stage support bbox rows, coalesced (one wave per row)
        const int lane = tid & 63;
        for (int r = wid; r < nry; r += 4) {
            const float* __restrict__ src = img + (mny + r) * W_ + mnx;
            float* __restrict__ dst = sBox + r * Lw;
            for (int c = lane; c < Lw; c += 64)
                dst[c] = src[c];
        }
        __syncthreads();
        // pass 1 gathers from LDS (nonzero-weight taps are inside bbox by
        // construction; zero-weight taps clamp to any valid slot)
        #pragma unroll
        for (int it = 0; it < PPT; ++it) {
            const int p = tid + it * NT;
            const int rx0 = min(max(cx0a[it] - mnx, 0), Lw - 1);
            const int rx1 = min(max(cx1a[it] - mnx, 0), Lw - 1);
            const int ry0 = min(max(cy0a[it] - mny, 0), nry - 1);
            const int ry1 = min(max(cy1a[it] - mny, 0), nry - 1);
            const float s = q0[it] * sBox[ry0 * Lw + rx0]
                          + q1[it] * sBox[ry0 * Lw + rx1]
                          + q2[it] * sBox[ry1 * Lw + rx0]
                          + q3[it] * sBox[ry1 * Lw + rx1];
            if (p < NPOS) sS1[p] = s;
        }
        __syncthreads();
    } else {
        // oversized support: direct global gather with zero-weight predication
        #pragma unroll
        for (int it = 0; it < PPT; ++it) {
            const int p = tid + it * NT;
            float s = 0.0f;
            if (q0[it] != 0.f || q1[it] != 0.f)
                s += q0[it] * img[cy0a[it] * W_ + cx0a[it]]
                   + q1[it] * img[cy0a[it] * W_ + cx1a[it]];
            if (q2[it] != 0.f || q3[it] != 0.f)
                s += q2[it] * img[cy1a[it] * W_ + cx0a[it]]
                   + q3[it] * img[cy1a[it] * W_ + cx1a[it]];
            if (p < NPOS) sS1[p] = s;
        }
        __syncthreads();
    }

    // pass 2: constant-weight 2x2 blend from LDS S1 region
    const float* Lr = sS1 + pr_o * REG + pc_o;
    o[pix] = w00 * Lr[0] + w01 * Lr[1] + w10 * Lr[REG] + w11 * Lr[REG + 1];
}

extern "C" void kernel_launch(void* const* d_in, const int* in_sizes, int n_in,
                              void* d_out, int out_size, void* d_ws, size_t ws_size,
                              hipStream_t stream) {
    const float* bevs   = (const float*)d_in[0];
    const float* tm     = (const float*)d_in[1];
    const int*   nat    = (const int*)d_in[2];
    const int*   center = (const int*)d_in[4];
    float* out = (float*)d_out;

    dim3 grid((H_ / TILE) * (W_ / TILE), A_ * B_ * K_, C_);
    dim3 block(NT);
    fafmimo_warp_kernel<<<grid, block, 0, stream>>>(bevs, tm, nat, center, out);
}

// Round 6
// 123.297 us; speedup vs baseline: 2.0591x; 2.0591x over previous
//
#include <hip/hip_runtime.h>

// Problem constants (from reference): A=5, B=2, K=5, C=13, H=W=256
constexpr int A_ = 5, B_ = 2, K_ = 5, C_ = 13, H_ = 256, W_ = 256;
constexpr int HW_ = H_ * W_;
constexpr int TILE = 32;
constexpr int REG = TILE + 1;            // 33 (tile + 1 halo for pass-2 taps)
constexpr int NPOS = REG * REG;          // 1089
constexpr int NT = 256;
constexpr int NPATCH = 5 * 5;            // 8x8 patches covering 40x40 >= 33x33
constexpr int NIT = 7;                   // ceil(25 patches / 4 waves)

// 8-byte vector load with only 4-byte alignment guarantee (backend emits
// dwordx2 if unaligned access mode is on, else two dwords — both correct)
typedef float float2u __attribute__((ext_vector_type(2), aligned(4)));

__global__ __launch_bounds__(NT)
void fafmimo_warp_kernel(const float* __restrict__ bevs,
                         const float* __restrict__ tm,
                         const int*   __restrict__ nat,
                         const int*   __restrict__ center_p,
                         float* __restrict__ out)
{
    const int tileIdx = blockIdx.x;      // 0..63 (8x8 tiles of 32x32 px)
    const int abk     = blockIdx.y;      // 0..49 == (a*B+b)*K + k
    const int ch      = blockIdx.z;      // 0..12
    const int a   = abk / (B_ * K_);
    const int rem = abk % (B_ * K_);
    const int b   = rem / K_;
    const int k   = rem % K_;

    const int center  = center_p[0];
    const int n_agent = nat[b * A_ + center];
    const bool masked = (a < n_agent) && ((a != center) || (k == K_ - 1));

    const int th0 = (tileIdx >> 3) * TILE;
    const int tw0 = (tileIdx & 7) * TILE;

    const int tid = threadIdx.x;
    const int rr  = tid >> 3;            // output row within tile, 0..31
    const int cg  = (tid & 7) << 2;      // output col group (float4), 0..28

    const float* __restrict__ img = bevs + (size_t)(abk * C_ + ch) * HW_;
    float*       __restrict__ o   = out  + (size_t)(abk * C_ + ch) * HW_;
    const int off = (th0 + rr) * W_ + tw0 + cg;

    if (!masked) {
        // straight copy of this channel tile (float4, coalesced)
        const float4 v = *reinterpret_cast<const float4*>(img + off);
        *reinterpret_cast<float4*>(o + off) = v;
        return;
    }

    // --- per-image transform params (trans_mats shape (A,K,B,4,4)) ---
    const int tb = ((a * K_ + k) * B_ + b) * 16;
    const float t00 = tm[tb + 0], t01 = tm[tb + 1], t03 = tm[tb + 3];
    const float t10 = tm[tb + 4], t11 = tm[tb + 5], t13 = tm[tb + 7];

    // Pass-2 (translation) in pixel units
    const float dx = 4.0f * t03;
    const float dy = -4.0f * t13;
    const float fxf = floorf(dx), fyf = floorf(dy);
    const int   fx = (int)fxf,    fy = (int)fyf;
    const float wx2 = dx - fxf,   wy2 = dy - fyf;
    const float w00 = (1.0f - wx2) * (1.0f - wy2);
    const float w01 = wx2 * (1.0f - wy2);
    const float w10 = (1.0f - wx2) * wy2;
    const float w11 = wx2 * wy2;

    // source coords: ix = t00*gx + t01*gy + cxk (verified formula R3-R5)
    const float cxk = 127.5f - 127.5f * (t00 + t01);
    const float cyk = 127.5f - 127.5f * (t10 + t11);

    __shared__ float lds[NPOS];
    __shared__ int   anyflag;
    if (tid == 0) anyflag = 0;

    // --- 2D wave-patch mapping: wave w handles patches w, w+4, ... ---
    const int wv = tid >> 6;             // wave 0..3
    const int l  = tid & 63;
    const int lr = l >> 3;               // in-patch row 0..7
    const int lc = l & 7;                // in-patch col 0..7

    int   lidx[NIT], oA[NIT], oB[NIT];
    float aAx[NIT], aAy[NIT], aBx[NIT], aBy[NIT];
    bool  hasAny = false;

    #pragma unroll
    for (int it = 0; it < NIT; ++it) {
        const int P  = wv + (it << 2);   // patch id 0..27
        const int Pr = P / 5;
        const int Pc = P - Pr * 5;
        const int pr = (Pr << 3) + lr;   // S1 row 0..39
        const int pc = (Pc << 3) + lc;   // S1 col 0..39
        const bool pv = (P < NPATCH) && (pr < REG) && (pc < REG);

        const int gyp = th0 + fy + pr;
        const int gxp = tw0 + fx + pc;
        const bool inreg = pv && (gyp >= 0) && (gyp < H_) &&
                                 (gxp >= 0) && (gxp < W_);
        const float ix = t00 * (float)gxp + t01 * (float)gyp + cxk;
        const float iy = t10 * (float)gxp + t11 * (float)gyp + cyk;
        const float x0f = floorf(ix), y0f = floorf(iy);
        const float wx = ix - x0f,    wy = iy - y0f;
        const int x0 = (int)x0f, y0 = (int)y0f;
        const int x1 = x0 + 1,   y1 = y0 + 1;
        const bool vx0 = (x0 >= 0) && (x0 < W_);
        const bool vx1 = (x1 >= 0) && (x1 < W_);
        const bool vy0 = (y0 >= 0) && (y0 < H_);
        const bool vy1 = (y1 >= 0) && (y1 < H_);
        const int cx0 = min(max(x0, 0), W_ - 1);
        const int cx1 = min(max(x1, 0), W_ - 1);
        const int cy0 = min(max(y0, 0), H_ - 1);
        const int cy1 = min(max(y1, 0), H_ - 1);
        const float m = inreg ? 1.0f : 0.0f;
        const float q0 = (1.0f - wx) * (1.0f - wy) * ((vx0 && vy0) ? m : 0.0f);
        const float q1 = wx * (1.0f - wy)          * ((vx1 && vy0) ? m : 0.0f);
        const float q2 = (1.0f - wx) * wy          * ((vx0 && vy1) ? m : 0.0f);
        const float q3 = wx * wy                   * ((vx1 && vy1) ? m : 0.0f);

        // fold x0/x1 taps into one 8B pair load at xs; weights select lanes
        const int xs = min(cx0, W_ - 2);
        oA[it] = cy0 * W_ + xs;
        oB[it] = cy1 * W_ + xs;
        aAx[it] = (cx0 == xs     ? q0 : 0.0f) + (cx1 == xs     ? q1 : 0.0f);
        aAy[it] = (cx0 == xs + 1 ? q0 : 0.0f) + (cx1 == xs + 1 ? q1 : 0.0f);
        aBx[it] = (cx0 == xs     ? q2 : 0.0f) + (cx1 == xs     ? q3 : 0.0f);
        aBy[it] = (cx0 == xs + 1 ? q2 : 0.0f) + (cx1 == xs + 1 ? q3 : 0.0f);
        lidx[it] = pv ? (pr * REG + pc) : -1;
        hasAny |= (aAx[it] != 0.f) || (aAy[it] != 0.f) ||
                  (aBx[it] != 0.f) || (aBy[it] != 0.f);
    }

    __syncthreads();
    if (hasAny) anyflag = 1;             // benign race: all writers store 1
    __syncthreads();

    if (!anyflag) {
        // whole S1 region has zero weight -> this channel tile is zeros
        *reinterpret_cast<float4*>(o + off) = make_float4(0.f, 0.f, 0.f, 0.f);
        return;
    }

    // pass 1: predicated paired gathers into LDS
    #pragma unroll
    for (int it = 0; it < NIT; ++it) {
        float s = 0.0f;
        if (aAx[it] != 0.f || aAy[it] != 0.f) {
            const float2u v = *reinterpret_cast<const float2u*>(img + oA[it]);
            s += aAx[it] * v.x + aAy[it] * v.y;
        }
        if (aBx[it] != 0.f || aBy[it] != 0.f) {
            const float2u v = *reinterpret_cast<const float2u*>(img + oB[it]);
            s += aBx[it] * v.x + aBy[it] * v.y;
        }
        if (lidx[it] >= 0) lds[lidx[it]] = s;
    }
    __syncthreads();

    // pass 2: constant-weight 2x2 blend from LDS, 4 outputs per thread
    const float* Lr0 = lds + rr * REG + cg;
    const float* Lr1 = Lr0 + REG;
    const float l0 = Lr0[0], l1 = Lr0[1], l2 = Lr0[2], l3 = Lr0[3], l4 = Lr0[4];
    const float m0 = Lr1[0], m1 = Lr1[1], m2 = Lr1[2], m3 = Lr1[3], m4 = Lr1[4];
    float4 v;
    v.x = w00 * l0 + w01 * l1 + w10 * m0 + w11 * m1;
    v.y = w00 * l1 + w01 * l2 + w10 * m1 + w11 * m2;
    v.z = w00 * l2 + w01 * l3 + w10 * m2 + w11 * m3;
    v.w = w00 * l3 + w01 * l4 + w10 * m3 + w11 * m4;
    *reinterpret_cast<float4*>(o + off) = v;
}

extern "C" void kernel_launch(void* const* d_in, const int* in_sizes, int n_in,
                              void* d_out, int out_size, void* d_ws, size_t ws_size,
                              hipStream_t stream) {
    const float* bevs   = (const float*)d_in[0];
    const float* tm     = (const float*)d_in[1];
    const int*   nat    = (const int*)d_in[2];
    const int*   center = (const int*)d_in[4];
    float* out = (float*)d_out;

    dim3 grid((H_ / TILE) * (W_ / TILE), A_ * B_ * K_, C_);
    dim3 block(NT);
    fafmimo_warp_kernel<<<grid, block, 0, stream>>>(bevs, tm, nat, center, out);
}

// Round 7
// 91.980 us; speedup vs baseline: 2.7602x; 1.3405x over previous
//
#include <hip/hip_runtime.h>

// Problem constants (from reference): A=5, B=2, K=5, C=13, H=W=256
constexpr int A_ = 5, B_ = 2, K_ = 5, C_ = 13, H_ = 256, W_ = 256;
constexpr int HW_ = H_ * W_;
constexpr int TILE = 32;
constexpr int REG = TILE + 1;            // 33 (tile + 1 halo for pass-2 taps)
constexpr int NPOS = REG * REG;          // 1089
constexpr int NT = 256;
constexpr int PPT = (NPOS + NT - 1) / NT; // 5 positions per thread

// 8-byte vector load with 4-byte alignment guarantee (gfx950 unaligned
// global access is legal; compiler emits global_load_dwordx2)
typedef float float2u __attribute__((ext_vector_type(2), aligned(4)));

__global__ __launch_bounds__(NT)
void fafmimo_warp_kernel(const float* __restrict__ bevs,
                         const float* __restrict__ tm,
                         const int*   __restrict__ nat,
                         const int*   __restrict__ center_p,
                         float* __restrict__ out)
{
    const int tileIdx = blockIdx.x;      // 0..63 (8x8 tiles of 32x32)
    const int abk     = blockIdx.y;      // 0..49 == (a*B+b)*K + k
    const int ch      = blockIdx.z;      // 0..12
    const int a   = abk / (B_ * K_);
    const int rem = abk % (B_ * K_);
    const int b   = rem / K_;
    const int k   = rem % K_;

    const int center  = center_p[0];
    const int n_agent = nat[b * A_ + center];
    const bool masked = (a < n_agent) && ((a != center) || (k == K_ - 1));

    const int th0 = (tileIdx >> 3) * TILE;
    const int tw0 = (tileIdx & 7) * TILE;

    const int tid = threadIdx.x;
    const int rr  = tid >> 3;            // output row within tile, 0..31
    const int cg  = (tid & 7) << 2;      // output col group (float4), 0..28

    const float* __restrict__ img = bevs + (size_t)(abk * C_ + ch) * HW_;
    float*       __restrict__ o   = out  + (size_t)(abk * C_ + ch) * HW_;
    const int off = (th0 + rr) * W_ + tw0 + cg;

    if (!masked) {
        // straight copy of this channel tile (float4, coalesced)
        const float4 v = *reinterpret_cast<const float4*>(img + off);
        *reinterpret_cast<float4*>(o + off) = v;
        return;
    }

    // --- per-image transform params (trans_mats shape (A,K,B,4,4)) ---
    const int tb = ((a * K_ + k) * B_ + b) * 16;
    const float t00 = tm[tb + 0], t01 = tm[tb + 1], t03 = tm[tb + 3];
    const float t10 = tm[tb + 4], t11 = tm[tb + 5], t13 = tm[tb + 7];

    // Pass-2 (translation) in pixel units
    const float dx = 4.0f * t03;
    const float dy = -4.0f * t13;
    const float fxf = floorf(dx), fyf = floorf(dy);
    const int   fx = (int)fxf,    fy = (int)fyf;
    const float wx2 = dx - fxf,   wy2 = dy - fyf;
    const float w00 = (1.0f - wx2) * (1.0f - wy2);
    const float w01 = wx2 * (1.0f - wy2);
    const float w10 = (1.0f - wx2) * wy2;
    const float w11 = wx2 * wy2;

    // source coords: ix = t00*gx + t01*gy + cxk (verified formula R3-R6)
    const float cxk = 127.5f - 127.5f * (t00 + t01);
    const float cyk = 127.5f - 127.5f * (t10 + t11);

    __shared__ float lds[NPOS];
    __shared__ int   anyflag;
    if (tid == 0) anyflag = 0;

    // --- pass-1 taps for the 33x33 S1 region (linear lane mapping) ---
    int   oA[PPT], oB[PPT];
    float aAx[PPT], aAy[PPT], aBx[PPT], aBy[PPT];
    bool  hasAny = false;
    #pragma unroll
    for (int it = 0; it < PPT; ++it) {
        const int p = tid + it * NT;
        const int pr = p / REG;
        const int pc = p - pr * REG;
        const int gyp = th0 + fy + pr;
        const int gxp = tw0 + fx + pc;
        const bool inreg = (p < NPOS) &&
                           (gyp >= 0) && (gyp < H_) && (gxp >= 0) && (gxp < W_);
        const float ix = t00 * (float)gxp + t01 * (float)gyp + cxk;
        const float iy = t10 * (float)gxp + t11 * (float)gyp + cyk;
        const float x0f = floorf(ix), y0f = floorf(iy);
        const float wx = ix - x0f,    wy = iy - y0f;
        const int x0 = (int)x0f, y0 = (int)y0f;
        const int x1 = x0 + 1,   y1 = y0 + 1;
        const bool vx0 = (x0 >= 0) && (x0 < W_);
        const bool vx1 = (x1 >= 0) && (x1 < W_);
        const bool vy0 = (y0 >= 0) && (y0 < H_);
        const bool vy1 = (y1 >= 0) && (y1 < H_);
        const int cx0 = min(max(x0, 0), W_ - 1);
        const int cx1 = min(max(x1, 0), W_ - 1);
        const int cy0 = min(max(y0, 0), H_ - 1);
        const int cy1 = min(max(y1, 0), H_ - 1);
        const float m = inreg ? 1.0f : 0.0f;
        const float q0 = (1.0f - wx) * (1.0f - wy) * ((vx0 && vy0) ? m : 0.0f);
        const float q1 = wx * (1.0f - wy)          * ((vx1 && vy0) ? m : 0.0f);
        const float q2 = (1.0f - wx) * wy          * ((vx0 && vy1) ? m : 0.0f);
        const float q3 = wx * wy                   * ((vx1 && vy1) ? m : 0.0f);

        // fold x0/x1 taps of each row into one 8B pair load at xs
        const int xs = min(max(x0, 0), W_ - 2);
        oA[it] = cy0 * W_ + xs;
        oB[it] = cy1 * W_ + xs;
        aAx[it] = (cx0 == xs     ? q0 : 0.0f) + (cx1 == xs     ? q1 : 0.0f);
        aAy[it] = (cx0 == xs + 1 ? q0 : 0.0f) + (cx1 == xs + 1 ? q1 : 0.0f);
        aBx[it] = (cx0 == xs     ? q2 : 0.0f) + (cx1 == xs     ? q3 : 0.0f);
        aBy[it] = (cx0 == xs + 1 ? q2 : 0.0f) + (cx1 == xs + 1 ? q3 : 0.0f);
        hasAny |= (aAx[it] != 0.f) || (aAy[it] != 0.f) ||
                  (aBx[it] != 0.f) || (aBy[it] != 0.f);
    }

    __syncthreads();
    if (hasAny) anyflag = 1;             // benign race: all writers store 1
    __syncthreads();

    if (!anyflag) {
        // whole S1 region has zero weight -> this channel tile is zeros
        *reinterpret_cast<float4*>(o + off) = make_float4(0.f, 0.f, 0.f, 0.f);
        return;
    }

    // pass 1: predicated paired gathers into LDS (10 loads max per thread)
    #pragma unroll
    for (int it = 0; it < PPT; ++it) {
        const int p = tid + it * NT;
        float s = 0.0f;
        if (aAx[it] != 0.f || aAy[it] != 0.f) {
            const float2u v = *reinterpret_cast<const float2u*>(img + oA[it]);
            s += aAx[it] * v.x + aAy[it] * v.y;
        }
        if (aBx[it] != 0.f || aBy[it] != 0.f) {
            const float2u v = *reinterpret_cast<const float2u*>(img + oB[it]);
            s += aBx[it] * v.x + aBy[it] * v.y;
        }
        if (p < NPOS) lds[p] = s;
    }
    __syncthreads();

    // pass 2: constant-weight 2x2 blend from LDS, 4 outputs per thread
    const float* Lr0 = lds + rr * REG + cg;
    const float* Lr1 = Lr0 + REG;
    const float l0 = Lr0[0], l1 = Lr0[1], l2 = Lr0[2], l3 = Lr0[3], l4 = Lr0[4];
    const float m0 = Lr1[0], m1 = Lr1[1], m2 = Lr1[2], m3 = Lr1[3], m4 = Lr1[4];
    float4 v;
    v.x = w00 * l0 + w01 * l1 + w10 * m0 + w11 * m1;
    v.y = w00 * l1 + w01 * l2 + w10 * m1 + w11 * m2;
    v.z = w00 * l2 + w01 * l3 + w10 * m2 + w11 * m3;
    v.w = w00 * l3 + w01 * l4 + w10 * m3 + w11 * m4;
    *reinterpret_cast<float4*>(o + off) = v;
}

extern "C" void kernel_launch(void* const* d_in, const int* in_sizes, int n_in,
                              void* d_out, int out_size, void* d_ws, size_t ws_size,
                              hipStream_t stream) {
    const float* bevs   = (const float*)d_in[0];
    const float* tm     = (const float*)d_in[1];
    const int*   nat    = (const int*)d_in[2];
    const int*   center = (const int*)d_in[4];
    float* out = (float*)d_out;

    dim3 grid((H_ / TILE) * (W_ / TILE), A_ * B_ * K_, C_);
    dim3 block(NT);
    fafmimo_warp_kernel<<<grid, block, 0, stream>>>(bevs, tm, nat, center, out);
}